// Round 6
// baseline (231.185 us; speedup 1.0000x reference)
//
#include <hip/hip_runtime.h>

// RelatEntAtt: E=4096, R=64, D=256. Fully fused recompute. No max-subtraction
// (|att| <~ 20, sums <~ 2e12, fp32-safe); exp2 with log2(e) folded into the
// adj-softmax output (leaky commutes with positive scale).
// R5 post-mortem: cross-XCD atomic RMW ping-pong (hAcc/lRacc) + per-cell
//   ds_read + 8 DPP ops/cell made kB memory/LDS-bound (VALUBusy 29%).
// R6: TRANSPOSED layout: lane = j (R=64 = wave). alog reduction becomes a
//   lane-local fma; h'/lR reductions become 1 wave-DPP-reduce per 64 cells;
//   h/invlR/W broadcast via v_readlane (VALU pipe, zero LDS in main loop).
//   Only atomics: lE_T/racc_T (coalesced, R2-proven) + combined alog (8 MB).

#define EN 4096
#define RN 64
#define DN 256
#define LOG2E 1.44269504088896340736f

__device__ __forceinline__ float ex2(float x){ return __builtin_amdgcn_exp2f(x); }
__device__ __forceinline__ float rl(float v, int srclane){
  return __int_as_float(__builtin_amdgcn_readlane(__float_as_int(v), srclane));
}
template<int CTRL>
__device__ __forceinline__ float dpp_add(float v){
  int m = __builtin_amdgcn_update_dpp(0, __float_as_int(v), CTRL, 0xf, 0xf, true);
  return v + __int_as_float(m);
}
// full 64-lane sum; result valid in lane 63
__device__ __forceinline__ float wave_sum64(float v){
  v = dpp_add<0x111>(v);   // row_shr:1
  v = dpp_add<0x112>(v);   // row_shr:2
  v = dpp_add<0x114>(v);   // row_shr:4
  v = dpp_add<0x118>(v);   // row_shr:8  -> lane15 of each row16 = row sum
  v = dpp_add<0x142>(v);   // row_bcast15 -> lane31 = rows0+1, lane63 = rows2+3
  v = dpp_add<0x143>(v);   // row_bcast31 -> lane63 = total
  return v;
}

// ---- s2[e,j] = softmax_j(adj[e,:]) * LOG2E ----
__global__ __launch_bounds__(256) void k_adj(const float* __restrict__ adj,
                                             float* __restrict__ s2){
  const int lane = threadIdx.x & 63;
  const int e = blockIdx.x*4 + (threadIdx.x >> 6);
  float a = adj[e*RN + lane];
  float ev = ex2(a * LOG2E);
  float s = ev;
  #pragma unroll
  for(int off = 32; off > 0; off >>= 1) s += __shfl_xor(s, off, 64);
  s2[e*RN + lane] = ev * (LOG2E / s);
}

// ---- rT[d][j] = r[j][d] ----
__global__ void kT(const float* __restrict__ r, float* __restrict__ rT){
  rT[blockIdx.x*RN + threadIdx.x] = r[threadIdx.x*DN + blockIdx.x];
}

// ---- kA: invlR[e,d] = 1/sum_j ev ; lE_T[d,j] += sum_e ev ----
// block: 8 e's x 32 d's; wave w owns d in [d0+w*8, d0+w*8+8), lane = j.
__global__ __launch_bounds__(256,2) void kA(const float* __restrict__ h,
                                            const float* __restrict__ rT,
                                            const float* __restrict__ s2,
                                            float* __restrict__ invlR,
                                            float* __restrict__ lE_T){
  const int tid  = threadIdx.x;
  const int w    = tid >> 6;
  const int lane = tid & 63;                 // = j
  const int e0   = blockIdx.x * 8;
  const int d0   = blockIdx.y * 32 + w*8;
  // lane L holds h[(e0+L>>3)][d0+(L&7)] for broadcast via readlane
  const float hreg = h[(e0 + (lane>>3))*DN + d0 + (lane&7)];
  float s2v[8];
  #pragma unroll
  for(int ee = 0; ee < 8; ee++) s2v[ee] = s2[(e0+ee)*RN + lane];
  float lrv = 0.f;                           // this lane's (ee,dd) lR total
  #pragma unroll 1
  for(int dd = 0; dd < 8; dd++){
    const int d = d0 + dd;
    const float rv = rT[d*RN + lane];
    float lEaccD = 0.f;
    #pragma unroll
    for(int ee = 0; ee < 8; ee++){
      float he = rl(hreg, ee*8 + dd);
      float t  = s2v[ee] * he * rv;
      float ev = ex2(fmaxf(t, 0.2f*t));
      lEaccD += ev;
      float tot = wave_sum64(ev);
      float s = rl(tot, 63);
      lrv = (lane == ee*8 + dd) ? s : lrv;
    }
    atomicAdd(&lE_T[d*RN + lane], lEaccD);
  }
  invlR[(e0 + (lane>>3))*DN + d0 + (lane&7)] = 1.0f / lrv;
}

// ---- kB: main fused sweep (transposed) ----
// per cell (e, j=lane, d): ev recomputed.
//   h'[e,d] = elu(h * sum_j ev/lE)   wave-reduce -> lane-held -> direct store
//   racc_T[d,j] += sum_e ev*invlR   lane-local over 8 e's, atomic per (wave,d)
//   alog[e,j] += sum_d ev*invlR*W_d  LANE-LOCAL fma; LDS combine + atomic
__global__ __launch_bounds__(256,2) void kB(const float* __restrict__ h,
                                            const float* __restrict__ rT,
                                            const float* __restrict__ s2,
                                            const float* __restrict__ invlR,
                                            const float* __restrict__ lE_T,
                                            const float* __restrict__ W,
                                            float* __restrict__ hout,
                                            float* __restrict__ alog,
                                            float* __restrict__ racc_T){
  __shared__ float apart[4][8][64];          // 8 KB
  const int tid  = threadIdx.x;
  const int w    = tid >> 6;
  const int lane = tid & 63;                 // = j
  const int e0   = blockIdx.x * 8;
  const int d0   = blockIdx.y * 32 + w*8;
  const float hreg  = h[(e0 + (lane>>3))*DN + d0 + (lane&7)];
  const float ilreg = invlR[(e0 + (lane>>3))*DN + d0 + (lane&7)];
  const float wreg  = W[d0 + (lane&7)];
  float s2v[8];
  #pragma unroll
  for(int ee = 0; ee < 8; ee++) s2v[ee] = s2[(e0+ee)*RN + lane];
  float aAcc[8] = {0.f,0.f,0.f,0.f,0.f,0.f,0.f,0.f};
  float hAll = 0.f;
  #pragma unroll 1
  for(int dd = 0; dd < 8; dd++){
    const int d = d0 + dd;
    const float rv  = rT[d*RN + lane];
    const float iev = 1.0f / lE_T[d*RN + lane];
    const float wd  = rl(wreg, dd);
    float rAccD = 0.f;
    #pragma unroll
    for(int ee = 0; ee < 8; ee++){
      float he = rl(hreg,  ee*8 + dd);
      float il = rl(ilreg, ee*8 + dd);
      float t  = s2v[ee] * he * rv;
      float ev = ex2(fmaxf(t, 0.2f*t));
      rAccD    = fmaf(ev, il, rAccD);          // att_R sum over e (this chunk)
      aAcc[ee] = fmaf(ev, il*wd, aAcc[ee]);    // alog partial, lane-local over d
      float hv = ev * iev;                      // att_E contribution
      float tot = wave_sum64(hv);
      float s = rl(tot, 63);
      hAll = (lane == ee*8 + dd) ? s : hAll;
    }
    atomicAdd(&racc_T[d*RN + lane], rAccD);
  }
  // h' direct store (each lane owns one (ee,dd); full j-sum already done)
  {
    float hp = hreg * hAll;
    hout[(e0 + (lane>>3))*DN + d0 + (lane&7)] =
        hp > 0.f ? hp : (ex2(hp*LOG2E) - 1.0f);
  }
  // alog: combine 4 waves in LDS, then one atomic per (e,j) per block
  #pragma unroll
  for(int ee = 0; ee < 8; ee++) apart[w][ee][lane] = aAcc[ee];
  __syncthreads();
  #pragma unroll
  for(int k = 0; k < 2; k++){
    int idx = k*256 + tid;
    int ee = idx >> 6, j = idx & 63;
    float s = apart[0][ee][j] + apart[1][ee][j] + apart[2][ee][j] + apart[3][ee][j];
    atomicAdd(&alog[(e0+ee)*RN + j], s);
  }
}

// ---- r' = elu(r * racc_T^T) ----
__global__ __launch_bounds__(256) void kR(const float* __restrict__ r,
                                          const float* __restrict__ racc_T,
                                          float* __restrict__ rout){
  int i = blockIdx.x*256 + threadIdx.x;      // i = j*256 + d
  int j = i >> 8, d = i & 255;
  float v = r[i] * racc_T[d*RN + j];
  rout[i] = v > 0.f ? v : (ex2(v*LOG2E) - 1.0f);
}

// ---- alpha: softmax over each contiguous 4096-chunk of flat alog ----
// (reference's reshape(R,E,1)+softmax(axis=1) == this on the e*64+j flat array;
//  b_lin dropped by shift invariance)
__global__ __launch_bounds__(256) void kAlpha(const float* __restrict__ alog,
                                              float* __restrict__ aout){
  const int rr = blockIdx.x, tid = threadIdx.x;
  const float* __restrict__ row = alog + rr*EN;
  float exv[16]; float s = 0.f;
  #pragma unroll
  for(int k = 0; k < 16; k++){
    float v = ex2(row[k*256 + tid] * LOG2E);
    exv[k] = v; s += v;
  }
  #pragma unroll
  for(int off = 32; off > 0; off >>= 1) s += __shfl_xor(s, off, 64);
  __shared__ float wsum[4];
  if((tid & 63) == 0) wsum[tid>>6] = s;
  __syncthreads();
  float inv = 1.0f / (wsum[0] + wsum[1] + wsum[2] + wsum[3]);
  float* __restrict__ orow = aout + rr*EN;
  #pragma unroll
  for(int k = 0; k < 16; k++) orow[k*256 + tid] = exv[k] * inv;
}

extern "C" void kernel_launch(void* const* d_in, const int* in_sizes, int n_in,
                              void* d_out, int out_size, void* d_ws, size_t ws_size,
                              hipStream_t stream){
  (void)in_sizes; (void)n_in; (void)out_size; (void)ws_size;
  const float* h   = (const float*)d_in[0];
  const float* r   = (const float*)d_in[1];
  const float* adj = (const float*)d_in[2];
  const float* W   = (const float*)d_in[3];
  // d_in[4] = b_lin: unused (softmax shift invariance)

  float* ws    = (float*)d_ws;
  float* s2    = ws;                  // EN*RN   = 262144
  float* rT    = s2 + EN*RN;          // DN*RN   = 16384
  float* invlR = rT + DN*RN;          // EN*DN   = 1048576
  // zeroed region (one memset):
  float* lE_T  = invlR + EN*DN;       // DN*RN   = 16384
  float* raccT = lE_T + DN*RN;        // DN*RN   = 16384
  float* alog  = raccT + DN*RN;       // EN*RN   = 262144

  float* hout = (float*)d_out;            // EN*DN
  float* rout = hout + EN*DN;             // RN*DN
  float* aout = rout + RN*DN;             // RN*EN

  hipMemsetAsync(lE_T, 0, size_t(2*DN*RN + EN*RN)*sizeof(float), stream);

  dim3 grid2(EN/8, DN/32);
  k_adj <<<EN/4,      256, 0, stream>>>(adj, s2);
  kT    <<<DN,         64, 0, stream>>>(r, rT);
  kA    <<<grid2,     256, 0, stream>>>(h, rT, s2, invlR, lE_T);
  kB    <<<grid2,     256, 0, stream>>>(h, rT, s2, invlR, lE_T, W, hout, alog, raccT);
  kR    <<<RN*DN/256, 256, 0, stream>>>(r, raccT, rout);
  kAlpha<<<RN,        256, 0, stream>>>(alog, aout);
}

// Round 7
// 213.867 us; speedup vs baseline: 1.0810x; 1.0810x over previous
//
#include <hip/hip_runtime.h>

// RelatEntAtt: E=4096, R=64, D=256. Fully fused recompute. No max-subtraction
// (|att| <~ 20, sums <~ 2e12, fp32-safe); exp2 with log2(e) folded into the
// adj-softmax output (leaky commutes with positive scale).
// History: R2 lane=d body: 52 VGPR, clean memory, but grid 512 = 2 blk/CU ->
//   VALUBusy 56%. R3 (launch_bounds 8) & R4 (CHB=2) spilled: compiler hoisted
//   all 4 j-tiles' loads. R5 j-split grid: cross-XCD atomic ping-pong. R6
//   lane=j: alog free but 2 wave-reductions/iter -> 52% VALU, dep-chain bound.
// R7: R2 body + CHB=4 (grid 1024, 4 blk/CU) + #pragma unroll 1 on jt loop
//   (blocks cross-tile hoisting) + launch_bounds(256,3) slack + precomputed
//   ilE (kills 16 v_rcp/tile) + he/il hoisted across tiles.

#define EN 4096
#define RN 64
#define DN 256
#define JT 16          // j-tile width
#define NJT (RN/JT)    // 4 tiles, looped serially (unroll 1)
#define LOG2E 1.44269504088896340736f
#define CHA 4          // e's per block in kA -> grid 1024
#define CHB 4          // e's per block in kB -> grid 1024

__device__ __forceinline__ float ex2(float x){ return __builtin_amdgcn_exp2f(x); }

template<int CTRL>
__device__ __forceinline__ float dpp_add(float v){
  int m = __builtin_amdgcn_update_dpp(0, __float_as_int(v), CTRL, 0xf, 0xf, true);
  return v + __int_as_float(m);
}
// lane (i%16)==15 ends with the sum of its 16-lane row
__device__ __forceinline__ float row16_sum(float v){
  v = dpp_add<0x111>(v);
  v = dpp_add<0x112>(v);
  v = dpp_add<0x114>(v);
  v = dpp_add<0x118>(v);
  return v;
}

// ---- s2[e,j] = softmax_j(adj[e,:]) * LOG2E ----
__global__ __launch_bounds__(256) void k_adj(const float* __restrict__ adj,
                                             float* __restrict__ s2){
  const int lane = threadIdx.x & 63;
  const int e = blockIdx.x*4 + (threadIdx.x >> 6);
  float a = adj[e*RN + lane];
  float ev = ex2(a * LOG2E);
  float s = ev;
  #pragma unroll
  for(int off = 32; off > 0; off >>= 1) s += __shfl_xor(s, off, 64);
  s2[e*RN + lane] = ev * (LOG2E / s);
}

// ---- kA: invlR[e,d] = 1/sum_j ev ; lE[j,d] += ev (atomics) ----
__global__ __launch_bounds__(256,3) void kA(const float* __restrict__ h,
                                            const float* __restrict__ r,
                                            const float* __restrict__ s2,
                                            float* __restrict__ invlR,
                                            float* __restrict__ lE){
  const int d  = threadIdx.x;
  const int e0 = blockIdx.x * CHA;
  __shared__ float s2s[CHA*RN];            // 256 floats
  s2s[d] = s2[e0*RN + d];
  __syncthreads();

  float he[CHA], lR[CHA];
  #pragma unroll
  for(int ee = 0; ee < CHA; ee++){ he[ee] = h[(e0+ee)*DN + d]; lR[ee] = 0.f; }

  #pragma unroll 1
  for(int jt = 0; jt < NJT; jt++){
    float rcol[JT], lEacc[JT];
    #pragma unroll
    for(int jj = 0; jj < JT; jj++){ rcol[jj] = r[(jt*JT+jj)*DN + d]; lEacc[jj] = 0.f; }
    #pragma unroll
    for(int ee = 0; ee < CHA; ee++){
      #pragma unroll
      for(int jj = 0; jj < JT; jj++){
        float t  = s2s[ee*RN + jt*JT + jj] * he[ee] * rcol[jj];
        float ev = ex2(fmaxf(t, 0.2f*t));
        lR[ee]    += ev;
        lEacc[jj] += ev;
      }
    }
    #pragma unroll
    for(int jj = 0; jj < JT; jj++) atomicAdd(&lE[(jt*JT+jj)*DN + d], lEacc[jj]);
  }
  #pragma unroll
  for(int ee = 0; ee < CHA; ee++) invlR[(e0+ee)*DN + d] = 1.0f / lR[ee];
}

// ---- ilE = 1/lE (removes per-tile v_rcp from kB) ----
__global__ __launch_bounds__(256) void kInv(const float* __restrict__ lE,
                                            float* __restrict__ ilE){
  int i = blockIdx.x*256 + threadIdx.x;
  ilE[i] = 1.0f / lE[i];
}

// ---- kB: main fused sweep (lane = d) ----
// per (e,d): ev recomputed; pR = ev*invlR (att_R), pE = ev*ilE (att_E)
//   h'[e,d]  = elu(h * sum_j pE)     serial j-sum, direct coalesced store
//   racc[j,d] += pR                  serial e-sum per tile, atomic flush
//   alog[e,j] = sum_d pR*W_d         row16 DPP + LDS partial combine
__global__ __launch_bounds__(256,3) void kB(const float* __restrict__ h,
                                            const float* __restrict__ r,
                                            const float* __restrict__ s2,
                                            const float* __restrict__ invlR,
                                            const float* __restrict__ ilE,
                                            const float* __restrict__ W,
                                            float* __restrict__ hout,
                                            float* __restrict__ alog,
                                            float* __restrict__ racc_g){
  const int tid  = threadIdx.x;            // = d
  const int lane = tid & 63;
  const int grp  = tid >> 4;               // 16 groups of 16 lanes
  const int e0   = blockIdx.x * CHB;
  __shared__ float s2s[CHB*RN];            // 256 floats
  __shared__ float apart[CHB*16*20];       // [ee][g][jj], g stride 20 (pad) 5 KB
  s2s[tid] = s2[e0*RN + tid];
  __syncthreads();

  const float wd = W[tid];
  float he[CHB], uu[CHB], il[CHB], sE[CHB];
  #pragma unroll
  for(int ee = 0; ee < CHB; ee++){
    he[ee] = h[(e0+ee)*DN + tid];
    il[ee] = invlR[(e0+ee)*DN + tid];
    uu[ee] = il[ee] * wd;
    sE[ee] = 0.f;
  }

  #pragma unroll 1
  for(int jt = 0; jt < NJT; jt++){
    float rcol[JT], ile[JT], rAcc[JT];
    #pragma unroll
    for(int jj = 0; jj < JT; jj++){
      const int j = jt*JT + jj;
      rcol[jj] = r[j*DN + tid];
      ile[jj]  = ilE[j*DN + tid];
      rAcc[jj] = 0.f;
    }
    #pragma unroll
    for(int ee = 0; ee < CHB; ee++){
      #pragma unroll
      for(int jg = 0; jg < JT/4; jg++){
        float4 st;
        #pragma unroll
        for(int jj4 = 0; jj4 < 4; jj4++){
          const int jj = jg*4 + jj4;
          float t  = s2s[ee*RN + jt*JT + jj] * he[ee] * rcol[jj];
          float ev = ex2(fmaxf(t, 0.2f*t));
          rAcc[jj] = fmaf(ev, il[ee], rAcc[jj]);   // att_R sum over e
          sE[ee]   = fmaf(ev, ile[jj], sE[ee]);    // att_E sum over j
          float rs = row16_sum(ev * uu[ee]);       // alog contribution
          if(jj4==0) st.x = rs; else if(jj4==1) st.y = rs;
          else if(jj4==2) st.z = rs; else st.w = rs;
        }
        if((lane & 15) == 15){
          *reinterpret_cast<float4*>(&apart[(ee*16 + grp)*20 + jg*4]) = st;
        }
      }
    }
    __syncthreads();
    if(tid < CHB*JT){                        // 64 threads: ee = tid>>4, jj = tid&15
      const int ee = tid >> 4, jj = tid & 15;
      float sum = 0.f;
      #pragma unroll
      for(int g = 0; g < 16; g++) sum += apart[(ee*16 + g)*20 + jj];
      alog[(e0+ee)*RN + jt*JT + jj] = sum;
    }
    __syncthreads();
    #pragma unroll
    for(int jj = 0; jj < JT; jj++) atomicAdd(&racc_g[(jt*JT+jj)*DN + tid], rAcc[jj]);
  }
  #pragma unroll
  for(int ee = 0; ee < CHB; ee++){
    float hp = he[ee] * sE[ee];
    hout[(e0+ee)*DN + tid] = hp > 0.f ? hp : (ex2(hp*LOG2E) - 1.0f);
  }
}

// ---- r' = elu(r * racc) ----
__global__ __launch_bounds__(256) void kR(const float* __restrict__ r,
                                          const float* __restrict__ racc,
                                          float* __restrict__ rout){
  int i = blockIdx.x*256 + threadIdx.x;
  float v = r[i] * racc[i];
  rout[i] = v > 0.f ? v : (ex2(v*LOG2E) - 1.0f);
}

// ---- alpha: softmax over each contiguous 4096-chunk of flat alog ----
// (reference's reshape(R,E,1)+softmax(axis=1) == this on the e*64+j flat array;
//  b_lin dropped by shift invariance)
__global__ __launch_bounds__(256) void kAlpha(const float* __restrict__ alog,
                                              float* __restrict__ aout){
  const int rr = blockIdx.x, tid = threadIdx.x;
  const float* __restrict__ row = alog + rr*EN;
  float exv[16]; float s = 0.f;
  #pragma unroll
  for(int k = 0; k < 16; k++){
    float v = ex2(row[k*256 + tid] * LOG2E);
    exv[k] = v; s += v;
  }
  #pragma unroll
  for(int off = 32; off > 0; off >>= 1) s += __shfl_xor(s, off, 64);
  __shared__ float wsum[4];
  if((tid & 63) == 0) wsum[tid>>6] = s;
  __syncthreads();
  float inv = 1.0f / (wsum[0] + wsum[1] + wsum[2] + wsum[3]);
  float* __restrict__ orow = aout + rr*EN;
  #pragma unroll
  for(int k = 0; k < 16; k++) orow[k*256 + tid] = exv[k] * inv;
}

extern "C" void kernel_launch(void* const* d_in, const int* in_sizes, int n_in,
                              void* d_out, int out_size, void* d_ws, size_t ws_size,
                              hipStream_t stream){
  (void)in_sizes; (void)n_in; (void)out_size; (void)ws_size;
  const float* h   = (const float*)d_in[0];
  const float* r   = (const float*)d_in[1];
  const float* adj = (const float*)d_in[2];
  const float* W   = (const float*)d_in[3];
  // d_in[4] = b_lin: unused (softmax shift invariance)

  float* ws    = (float*)d_ws;
  float* s2    = ws;                  // EN*RN   = 262144
  float* invlR = s2 + EN*RN;          // EN*DN   = 1048576
  float* ilE   = invlR + EN*DN;       // RN*DN   = 16384
  float* alog  = ilE + RN*DN;         // EN*RN   = 262144
  // zeroed region (one memset):
  float* lE    = alog + EN*RN;        // RN*DN   = 16384
  float* racc  = lE + RN*DN;          // RN*DN   = 16384

  float* hout = (float*)d_out;            // EN*DN
  float* rout = hout + EN*DN;             // RN*DN
  float* aout = rout + RN*DN;             // RN*EN

  hipMemsetAsync(lE, 0, size_t(2*RN*DN)*sizeof(float), stream);

  k_adj <<<EN/4,      256, 0, stream>>>(adj, s2);
  kA    <<<EN/CHA,    256, 0, stream>>>(h, r, s2, invlR, lE);
  kInv  <<<RN*DN/256, 256, 0, stream>>>(lE, ilE);
  kB    <<<EN/CHB,    256, 0, stream>>>(h, r, s2, invlR, ilE, W, hout, alog, racc);
  kR    <<<RN*DN/256, 256, 0, stream>>>(r, racc, rout);
  kAlpha<<<RN,        256, 0, stream>>>(alog, aout);
}